// Round 16
// baseline (215.328 us; speedup 1.0000x reference)
//
#include <hip/hip_runtime.h>
#include <hip/hip_bf16.h>

// NeuralFieldCosmo — R16: R15 retry (R14 base, verified 214us) with the
// compile fix: __hip_bfloat162 is not trivially copyable -> use
// __builtin_memcpy for the bit extraction (folds to a register move).
// Change under test (unchanged from R15): replace software f2bf RNE pack
// with library __float22bfloat162_rn (compiler-emitted v_cvt_pk_bf16_f32)
// at the two HOT sites (ln_relu_pack, epilogue store) — deletes ~100
// VALU/tile (~25%) from a VALU-issue-bound kernel (R14: VALUBusy 55%).
// Hand-written cvt_pk ASM stays BANNED (R8/R9 NaN); this is the
// defined-semantics library path. Staging keeps f2bf (cold).
// Ledger: MFMA 16x16x16bf16 layout verified R4-R14. launch_bounds(256,2)
// + consts in LDS = spill-free (R13/R14: VGPR 104-128, FETCH ~57-61MB).
// Spill tell = FETCH > 100 MB.

typedef __attribute__((ext_vector_type(4))) short short4v;   // 4 bf16
typedef __attribute__((ext_vector_type(4))) float float4v;
typedef __attribute__((ext_vector_type(4))) unsigned uint4v;
typedef __attribute__((ext_vector_type(2))) unsigned uint2v;

constexpr float LN_EPS   = 1e-5f;
constexpr float LOG2E_X2 = 2.8853900817779268f;  // 2*log2(e)

// RNE float -> bf16 bits (staging-only now; verified R4-R14)
__device__ __forceinline__ unsigned f2bf(float x) {
  unsigned u = __builtin_bit_cast(unsigned, x);
  u += 0x7FFFu + ((u >> 16) & 1u);
  return u >> 16;
}
__device__ __forceinline__ unsigned pack2(float lo, float hi) {
  return f2bf(lo) | (f2bf(hi) << 16);
}
// HOT pack: compiler-emitted v_cvt_pk_bf16_f32 (RNE), low 16 bits = lo.
__device__ __forceinline__ unsigned packc(float lo, float hi) {
  float2 v; v.x = lo; v.y = hi;
  const __hip_bfloat162 b = __float22bfloat162_rn(v);
  static_assert(sizeof(__hip_bfloat162) == 4, "bf16x2 must be 4 bytes");
  unsigned r;
  __builtin_memcpy(&r, &b, 4);   // byte copy: legal for any object, folds away
  return r;
}
__device__ __forceinline__ float bflo2f(unsigned u) {
  return __builtin_bit_cast(float, u << 16);
}
__device__ __forceinline__ float bfhi2f(unsigned u) {
  return __builtin_bit_cast(float, u & 0xFFFF0000u);
}

__device__ __forceinline__ float4v mfma16(short4v a, short4v b, float4v c) {
#if __has_builtin(__builtin_amdgcn_mfma_f32_16x16x16bf16_1k)
  return __builtin_amdgcn_mfma_f32_16x16x16bf16_1k(a, b, c, 0, 0, 0);
#else
  float4v d;
  asm volatile("v_mfma_f32_16x16x16_bf16 %0, %1, %2, %3\n\ts_nop 7\n\ts_nop 7"
               : "=&v"(d) : "v"(a), "v"(b), "v"(c));
  return d;
#endif
}

// LN over 32 ch (8/lane across quads), affine (packed bf16 g,be), relu,
// pack to two K-half B-frags. Same math as R7-R14; pack via packc.
__device__ __forceinline__ void ln_relu_pack(const float* hv, uint4v gp,
                                             uint4v bp, short4v* bh) {
  float sum = 0.f, ss = 0.f;
#pragma unroll
  for (int s = 0; s < 8; ++s) { sum += hv[s]; ss += hv[s] * hv[s]; }
  sum += __shfl_xor(sum, 16);  ss += __shfl_xor(ss, 16);
  sum += __shfl_xor(sum, 32);  ss += __shfl_xor(ss, 32);
  const float m   = sum * (1.0f / 32.0f);
  const float var = fmaxf(ss * (1.0f / 32.0f) - m * m, 0.f);
  const float rs  = rsqrtf(var + LN_EPS);
#pragma unroll
  for (int h = 0; h < 2; ++h) {
    float y[4];
#pragma unroll
    for (int j = 0; j < 4; ++j) {
      const int s = h * 4 + j;
      const float g  = (s & 1) ? bfhi2f(gp[s >> 1]) : bflo2f(gp[s >> 1]);
      const float be = (s & 1) ? bfhi2f(bp[s >> 1]) : bflo2f(bp[s >> 1]);
      y[j] = fmaxf((hv[s] - m) * rs * g + be, 0.f);
    }
    uint2v u;
    u[0] = packc(y[0], y[1]);
    u[1] = packc(y[2], y[3]);
    bh[h] = __builtin_bit_cast(short4v, u);
  }
}

// ---------------- CSR build ----------------

// vectorized histogram: 4 edges/thread via int4
__global__ void nf_hist(const int* __restrict__ out_edges, int* __restrict__ counts, int E) {
  const int t4 = (blockIdx.x * blockDim.x + threadIdx.x) * 4;
  if (t4 + 3 < E) {
    const int4 v = *(const int4*)(out_edges + t4);
    atomicAdd(&counts[v.x], 1);
    atomicAdd(&counts[v.y], 1);
    atomicAdd(&counts[v.z], 1);
    atomicAdd(&counts[v.w], 1);
  } else {
    for (int i = t4; i < E; ++i) atomicAdd(&counts[out_edges[i]], 1);
  }
}

__global__ void nf_alloc(const int* __restrict__ counts, int* __restrict__ offsets,
                         int* __restrict__ cursor, int* __restrict__ total, int N) {
  const int i = blockIdx.x * blockDim.x + threadIdx.x;
  const int lane = threadIdx.x & 63;
  int c = (i < N) ? counts[i] : 0;
  int sc = c;
#pragma unroll
  for (int d = 1; d < 64; d <<= 1) {
    int v = __shfl_up(sc, d);
    if (lane >= d) sc += v;
  }
  const int excl = sc - c;
  const int wtot = __shfl(sc, 63);
  int base = 0;
  if (lane == 0) base = atomicAdd(total, wtot);
  base = __shfl(base, 0);
  if (i < N) {
    offsets[i] = base + excl;
    cursor[i]  = base + excl;
  }
}

// ---------------- main compute ----------------
// SCATTER_MODE: 0 = CSR-ordered bf16 stream, 1 = direct f32 atomics fallback

template <int SCATTER_MODE>
__global__ __launch_bounds__(256, 2)   // cap 256: spill-free (R13/R14)
void nf_main(const int* __restrict__ in_edges,
             const int* __restrict__ out_edges,
             const float* __restrict__ ef,
             const float* __restrict__ coords,
             const float* __restrict__ W1, const float* __restrict__ b1,
             const float* __restrict__ g1, const float* __restrict__ be1,
             const float* __restrict__ W2, const float* __restrict__ b2,
             const float* __restrict__ g2, const float* __restrict__ be2,
             const float* __restrict__ W3, const float* __restrict__ b3,
             void* __restrict__ out_ch,   // mode0: unsigned[E][8] bf16x2 ; mode1: float sums (d_out)
             int* __restrict__ aux,       // mode1: counts
             int* __restrict__ cursor,    // mode0: [N]
             int E, int ntiles)
{
  // W3 A-fragments (prescaled 2log2e), per (o, lane): 16B = 8 bf16 {k=4q+j+16h}
  __shared__ __align__(16) unsigned sA3[16 * 64 * 4];   // 16 KB
  __shared__ __align__(16) float    sB3f[16 * 4 * 4];   // 2log2e*b3, f32
  __shared__ __align__(16) unsigned sC1[4][16];  // w1p[3][4], b1p[4]
  __shared__ __align__(16) unsigned sC2[4][16];  // g1p, be1p, g2p, be2p
  __shared__ __align__(16) unsigned sC3[4][4];   // b2p

  const int t    = threadIdx.x;
  const int l    = t & 63;
  const int q    = l >> 4;     // lane quad (channel/row group)
  const int ecol = l & 15;     // edge column within tile

  // ---- one-time LDS staging (identical to R7-R14, verified; f2bf ok here) ----
#pragma unroll
  for (int rep = 0; rep < 4; ++rep) {
    const int idx = rep * 256 + t;          // (o, lane)
    const int o = idx >> 6, ll = idx & 63;
    const int qq = ll >> 4, ec = ll & 15;
    uint4v w;
#pragma unroll
    for (int h = 0; h < 2; ++h)
#pragma unroll
      for (int jp = 0; jp < 2; ++jp) {
        const float lo = LOG2E_X2 * W3[(4 * qq + 2 * jp     + 16 * h) * 256 + o * 16 + ec];
        const float hi = LOG2E_X2 * W3[(4 * qq + 2 * jp + 1 + 16 * h) * 256 + o * 16 + ec];
        w[h * 2 + jp] = pack2(lo, hi);
      }
    *(uint4v*)&sA3[idx * 4] = w;
  }
  if (t < 64) {
    const int o = t >> 2, qq = t & 3;
    float4v bb;
#pragma unroll
    for (int r = 0; r < 4; ++r) bb[r] = LOG2E_X2 * b3[o * 16 + 4 * qq + r];
    *(float4v*)&sB3f[t * 4] = bb;
  }
  if (t < 4) {
    const int qq = t;
#pragma unroll
    for (int i = 0; i < 4; ++i) {
      const int base = (i < 2) ? (4 * qq + 2 * i) : (4 * qq + 16 + 2 * (i - 2));
      sC1[qq][i]      = pack2(W1[base],      W1[base + 1]);
      sC1[qq][4 + i]  = pack2(W1[32 + base], W1[33 + base]);
      sC1[qq][8 + i]  = pack2(W1[64 + base], W1[65 + base]);
      sC1[qq][12 + i] = pack2(b1[base],      b1[base + 1]);
      sC2[qq][i]      = pack2(g1[base],      g1[base + 1]);
      sC2[qq][4 + i]  = pack2(be1[base],     be1[base + 1]);
      sC2[qq][8 + i]  = pack2(g2[base],      g2[base + 1]);
      sC2[qq][12 + i] = pack2(be2[base],     be2[base + 1]);
      sC3[qq][i]      = pack2(b2[base],      b2[base + 1]);
    }
  }

  // L2 A-frags in regs (8 VGPR): A[m=ch_out][k=ch_in] = W2[k][m]
  short4v a2[2][2];
#pragma unroll
  for (int t2 = 0; t2 < 2; ++t2)
#pragma unroll
    for (int h = 0; h < 2; ++h) {
      short4v v;
#pragma unroll
      for (int j = 0; j < 4; ++j)
        v[j] = (short)f2bf(W2[(4 * q + j + 16 * h) * 32 + ecol + 16 * t2]);
      a2[t2][h] = v;
    }

  __syncthreads();

  // front: L1 -> LN1 -> L2 -> LN2 -> bh[2]
  auto front = [&](float x0, float x1, float x2, short4v* bh) {
    const uint4v w1r0 = *(const uint4v*)&sC1[q][0];
    const uint4v w1r1 = *(const uint4v*)&sC1[q][4];
    const uint4v w1r2 = *(const uint4v*)&sC1[q][8];
    const uint4v b1v  = *(const uint4v*)&sC1[q][12];
    float hv[8];
#pragma unroll
    for (int i = 0; i < 4; ++i) {
      hv[2 * i]     = bflo2f(b1v[i]) + x0 * bflo2f(w1r0[i])
                    + x1 * bflo2f(w1r1[i]) + x2 * bflo2f(w1r2[i]);
      hv[2 * i + 1] = bfhi2f(b1v[i]) + x0 * bfhi2f(w1r0[i])
                    + x1 * bfhi2f(w1r1[i]) + x2 * bfhi2f(w1r2[i]);
    }
    {
      const uint4v g1v  = *(const uint4v*)&sC2[q][0];
      const uint4v be1v = *(const uint4v*)&sC2[q][4];
      ln_relu_pack(hv, g1v, be1v, bh);
    }
    {
      const uint4v b2v = *(const uint4v*)&sC3[q][0];
#pragma unroll
      for (int t2 = 0; t2 < 2; ++t2) {
        float4v c;
        c[0] = bflo2f(b2v[t2 * 2]);     c[1] = bfhi2f(b2v[t2 * 2]);
        c[2] = bflo2f(b2v[t2 * 2 + 1]); c[3] = bfhi2f(b2v[t2 * 2 + 1]);
        c = mfma16(a2[t2][0], bh[0], c);
        c = mfma16(a2[t2][1], bh[1], c);
        hv[t2 * 4 + 0] = c[0]; hv[t2 * 4 + 1] = c[1];
        hv[t2 * 4 + 2] = c[2]; hv[t2 * 4 + 3] = c[3];
      }
    }
    {
      const uint4v g2v  = *(const uint4v*)&sC2[q][8];
      const uint4v be2v = *(const uint4v*)&sC2[q][12];
      ln_relu_pack(hv, g2v, be2v, bh);
    }
  };

  const int gwave  = (blockIdx.x * blockDim.x + t) >> 6;
  const int nwaves = (gridDim.x * blockDim.x) >> 6;

  // ---- skewed-pipeline prologue (R14 structure, verified) ----
  int tile = gwave;
  bool validC = false; int oeC = 0;
  short4v bhC[2] = {};
  float4v f4C = {};
  bool validN = false; int ieN = 0, oeN = 0;
  float xN0 = 0.f, xN1 = 0.f, xN2 = 0.f;

  if (tile < ntiles) {
    const int eI = tile * 16 + ecol;
    validC = eI < E;
    const int eS = validC ? eI : 0;
    const int ie = in_edges[eS]; oeC = out_edges[eS];
    const float x0 = coords[3 * eS], x1 = coords[3 * eS + 1], x2 = coords[3 * eS + 2];
    f4C = *(const float4v*)(ef + (size_t)ie * 16 + 4 * q);
    front(x0, x1, x2, bhC);
  }
  if (tile + nwaves < ntiles) {
    const int eI = (tile + nwaves) * 16 + ecol;
    validN = eI < E;
    const int eS = validN ? eI : 0;
    ieN = in_edges[eS]; oeN = out_edges[eS];
    xN0 = coords[3 * eS]; xN1 = coords[3 * eS + 1]; xN2 = coords[3 * eS + 2];
  }

  for (; tile < ntiles; tile += nwaves) {
    const int tn  = tile + nwaves;       // tile whose front runs this iter
    const int tnn = tile + 2 * nwaves;   // tile whose idx/coords prefetch now

    // ---- issue next tile's feature gather (consumed next iteration) ----
    float4v f4N = {};
    if (tn < ntiles)
      f4N = *(const float4v*)(ef + (size_t)ieN * 16 + 4 * q);

    // ---- CSR slot for CURRENT tile ----
    int pos = 0;
    if (SCATTER_MODE == 0 && q == 0 && validC)
      pos = atomicAdd(&cursor[oeC], 1);

    // ---- prefetch tile t+2 idx/coords ----
    bool validNN = false; int ieNN = 0, oeNN = 0;
    float xNN0 = 0.f, xNN1 = 0.f, xNN2 = 0.f;
    if (tnn < ntiles) {
      const int eI = tnn * 16 + ecol;
      validNN = eI < E;
      const int eS = validNN ? eI : 0;
      ieNN = in_edges[eS]; oeNN = out_edges[eS];
      xNN0 = coords[3 * eS]; xNN1 = coords[3 * eS + 1]; xNN2 = coords[3 * eS + 2];
    }

    // ---- front(t+1): long-latency chains issue first... ----
    short4v bhN[2] = {};
    if (tn < ntiles)
      front(xN0, xN1, xN2, bhN);

    // ---- ...epilogue(t): independent ILP-rich stream fills the stalls ----
    const float sumf = (f4C[0] + f4C[1]) + (f4C[2] + f4C[3]);
#pragma unroll
    for (int og = 0; og < 4; ++og) {
      float pr[4];
#pragma unroll
      for (int r = 0; r < 4; ++r) {
        const int o = og * 4 + r;
        const uint4v av = *(const uint4v*)&sA3[(o * 64 + l) * 4];
        float4v c = *(const float4v*)&sB3f[(o * 4 + q) * 4];
        uint2v t0; t0[0] = av[0]; t0[1] = av[1];
        uint2v t1; t1[0] = av[2]; t1[1] = av[3];
        const short4v a30 = __builtin_bit_cast(short4v, t0);
        const short4v a31 = __builtin_bit_cast(short4v, t1);
        c = mfma16(a30, bhC[0], c);
        c = mfma16(a31, bhC[1], c);
        float dot = 0.f;
#pragma unroll
        for (int j = 0; j < 4; ++j) {
          const float e = __builtin_amdgcn_exp2f(c[j]);
          dot = fmaf(f4C[j], __builtin_amdgcn_rcpf(e + 1.0f), dot);
        }
        pr[r] = fmaf(-2.0f, dot, sumf);
      }
#pragma unroll
      for (int r = 0; r < 4; ++r) {
        pr[r] += __shfl_xor(pr[r], 16);
        pr[r] += __shfl_xor(pr[r], 32);
      }
      if (SCATTER_MODE == 0) {
        if (q == 0 && validC) {
          uint2v s;
          s[0] = packc(pr[0], pr[1]);
          s[1] = packc(pr[2], pr[3]);
          *(uint2v*)((unsigned*)out_ch + (size_t)pos * 8 + og * 2) = s;
        }
      } else {
        if (q == 0 && validC) {
          float* sums = (float*)out_ch;
#pragma unroll
          for (int r = 0; r < 4; ++r)
            atomicAdd(&sums[(size_t)oeC * 16 + og * 4 + r], pr[r]);
        }
      }
    }
    if (SCATTER_MODE == 1) {
      if (q == 0 && validC) atomicAdd(&aux[oeC], 1);
    }

    // ---- rotate pipeline state ----
    bhC[0] = bhN[0]; bhC[1] = bhN[1];
    f4C = f4N; oeC = oeN; validC = validN;
    ieN = ieNN; oeN = oeNN; validN = validNN;
    xN0 = xNN0; xN1 = xNN1; xN2 = xNN2;
  }
}

// ---------------- per-node reduce (CSR path, bf16 rows) ----------------
// 8 threads/node, each handles 2 channels (one packed uint per edge-row).

__global__ __launch_bounds__(256)
void nf_reduce(const unsigned* __restrict__ out_chb, const int* __restrict__ counts,
               const int* __restrict__ offsets, float* __restrict__ out, int N) {
  const int gid = blockIdx.x * 32 + (threadIdx.x >> 3);  // node
  const int op  = threadIdx.x & 7;                       // channel pair
  if (gid >= N) return;
  const int deg = counts[gid];
  const int off = offsets[gid];
  float a0 = 0.f, a1 = 0.f;
  for (int d = 0; d < deg; ++d) {
    const unsigned u = out_chb[(size_t)(off + d) * 8 + op];
    a0 += bflo2f(u);
    a1 += bfhi2f(u);
  }
  const float inv = 1.0f / fmaxf((float)deg, 1.0f);
  float2 r; r.x = a0 * inv; r.y = a1 * inv;
  *(float2*)(out + (size_t)gid * 16 + 2 * op) = r;
}

// fallback divide
__global__ void nf_final(float* __restrict__ out, const int* __restrict__ counts, int n) {
  int i = blockIdx.x * blockDim.x + threadIdx.x;
  if (i < n) {
    float c = (float)counts[i >> 4];
    out[i] = out[i] / fmaxf(c, 1.0f);
  }
}

extern "C" void kernel_launch(void* const* d_in, const int* in_sizes, int n_in,
                              void* d_out, int out_size, void* d_ws, size_t ws_size,
                              hipStream_t stream) {
  const int*   in_edges  = (const int*)d_in[0];
  const int*   out_edges = (const int*)d_in[1];
  const float* ef        = (const float*)d_in[2];
  const float* coords    = (const float*)d_in[3];
  const float* W1  = (const float*)d_in[4];
  const float* b1  = (const float*)d_in[5];
  const float* g1  = (const float*)d_in[6];
  const float* be1 = (const float*)d_in[7];
  const float* W2  = (const float*)d_in[8];
  const float* b2  = (const float*)d_in[9];
  const float* g2  = (const float*)d_in[10];
  const float* be2 = (const float*)d_in[11];
  const float* W3  = (const float*)d_in[12];
  const float* b3  = (const float*)d_in[13];

  const int E = in_sizes[0];
  const int N = in_sizes[2] / 16;
  const int ntiles = (E + 15) / 16;
  float* out = (float*)d_out;

  // ws: out_chb [8E u32 bf16x2] | counts [N] | total [1] | offsets [N] | cursor [N]
  const size_t need = ((size_t)E * 8 + 3 * (size_t)N + 1) * 4;

  if (ws_size >= need) {
    unsigned* out_chb = (unsigned*)d_ws;
    int*      counts  = (int*)(out_chb + (size_t)E * 8);
    int*      total   = counts + N;
    int*      offsets = total + 1;
    int*      cursor  = offsets + N;

    // zero counts + total only (offsets/cursor fully written by nf_alloc)
    (void)hipMemsetAsync(counts, 0, ((size_t)N + 1) * sizeof(int), stream);
    nf_hist<<<(E / 4 + 255) / 256 + 1, 256, 0, stream>>>(out_edges, counts, E);
    nf_alloc<<<(N + 255) / 256, 256, 0, stream>>>(counts, offsets, cursor, total, N);
    nf_main<0><<<2048, 256, 0, stream>>>(in_edges, out_edges, ef, coords,
                                         W1, b1, g1, be1, W2, b2, g2, be2, W3, b3,
                                         out_chb, nullptr, cursor, E, ntiles);
    nf_reduce<<<(N + 31) / 32, 256, 0, stream>>>(out_chb, counts, offsets, out, N);
  } else {
    // fallback: direct f32 atomics
    int* counts = (int*)d_ws;
    (void)hipMemsetAsync(out, 0, (size_t)out_size * sizeof(float), stream);
    (void)hipMemsetAsync(counts, 0, (size_t)N * sizeof(int), stream);
    nf_main<1><<<2048, 256, 0, stream>>>(in_edges, out_edges, ef, coords,
                                         W1, b1, g1, be1, W2, b2, g2, be2, W3, b3,
                                         out, counts, nullptr, E, ntiles);
    nf_final<<<(out_size + 255) / 256, 256, 0, stream>>>(out, counts, out_size);
  }
}

// Round 17
// 211.112 us; speedup vs baseline: 1.0200x; 1.0200x over previous
//
#include <hip/hip_runtime.h>
#include <hip/hip_bf16.h>

// NeuralFieldCosmo — R17: plumbing round. nf_main BYTE-IDENTICAL to R16
// (verified 215us total, nf_main ~160us, absmax 0.046875) except grid
// 2048->1024 (exactly 4 blocks/CU resident = one scheduling round).
// nf_reduce: 2 threads/node with uint4 loads (was 8 threads x dword) —
// 4x fewer load ops for the same 32MB.
// nf_main plateau evidence: VALUBusy 53%, DS-pipe est ~74us, MfmaUtil 9%,
// HBM 10% — latency-bound at 4 waves/SIMD; dual-tile (x3), skew, VALU cuts
// all explored; remaining waste is plumbing (~55us).
// Ledger: cvt_pk raw ASM banned (R8/R9 NaN); f2bf + __float22bfloat162_rn
// verified; MFMA 16x16x16bf16 layout verified R4-R16; launch_bounds(256,2)
// + consts in LDS = spill-free (VGPR 104, FETCH ~57MB).

typedef __attribute__((ext_vector_type(4))) short short4v;   // 4 bf16
typedef __attribute__((ext_vector_type(4))) float float4v;
typedef __attribute__((ext_vector_type(4))) unsigned uint4v;
typedef __attribute__((ext_vector_type(2))) unsigned uint2v;

constexpr float LN_EPS   = 1e-5f;
constexpr float LOG2E_X2 = 2.8853900817779268f;  // 2*log2(e)

// RNE float -> bf16 bits (staging; verified R4-R16)
__device__ __forceinline__ unsigned f2bf(float x) {
  unsigned u = __builtin_bit_cast(unsigned, x);
  u += 0x7FFFu + ((u >> 16) & 1u);
  return u >> 16;
}
__device__ __forceinline__ unsigned pack2(float lo, float hi) {
  return f2bf(lo) | (f2bf(hi) << 16);
}
// HOT pack: library bf16x2 cvt (RNE), low 16 bits = lo. Verified R16.
__device__ __forceinline__ unsigned packc(float lo, float hi) {
  float2 v; v.x = lo; v.y = hi;
  const __hip_bfloat162 b = __float22bfloat162_rn(v);
  static_assert(sizeof(__hip_bfloat162) == 4, "bf16x2 must be 4 bytes");
  unsigned r;
  __builtin_memcpy(&r, &b, 4);
  return r;
}
__device__ __forceinline__ float bflo2f(unsigned u) {
  return __builtin_bit_cast(float, u << 16);
}
__device__ __forceinline__ float bfhi2f(unsigned u) {
  return __builtin_bit_cast(float, u & 0xFFFF0000u);
}

__device__ __forceinline__ float4v mfma16(short4v a, short4v b, float4v c) {
#if __has_builtin(__builtin_amdgcn_mfma_f32_16x16x16bf16_1k)
  return __builtin_amdgcn_mfma_f32_16x16x16bf16_1k(a, b, c, 0, 0, 0);
#else
  float4v d;
  asm volatile("v_mfma_f32_16x16x16_bf16 %0, %1, %2, %3\n\ts_nop 7\n\ts_nop 7"
               : "=&v"(d) : "v"(a), "v"(b), "v"(c));
  return d;
#endif
}

// LN over 32 ch (8/lane across quads), affine (packed bf16 g,be), relu,
// pack to two K-half B-frags. IDENTICAL to R16 (verified).
__device__ __forceinline__ void ln_relu_pack(const float* hv, uint4v gp,
                                             uint4v bp, short4v* bh) {
  float sum = 0.f, ss = 0.f;
#pragma unroll
  for (int s = 0; s < 8; ++s) { sum += hv[s]; ss += hv[s] * hv[s]; }
  sum += __shfl_xor(sum, 16);  ss += __shfl_xor(ss, 16);
  sum += __shfl_xor(sum, 32);  ss += __shfl_xor(ss, 32);
  const float m   = sum * (1.0f / 32.0f);
  const float var = fmaxf(ss * (1.0f / 32.0f) - m * m, 0.f);
  const float rs  = rsqrtf(var + LN_EPS);
#pragma unroll
  for (int h = 0; h < 2; ++h) {
    float y[4];
#pragma unroll
    for (int j = 0; j < 4; ++j) {
      const int s = h * 4 + j;
      const float g  = (s & 1) ? bfhi2f(gp[s >> 1]) : bflo2f(gp[s >> 1]);
      const float be = (s & 1) ? bfhi2f(bp[s >> 1]) : bflo2f(bp[s >> 1]);
      y[j] = fmaxf((hv[s] - m) * rs * g + be, 0.f);
    }
    uint2v u;
    u[0] = packc(y[0], y[1]);
    u[1] = packc(y[2], y[3]);
    bh[h] = __builtin_bit_cast(short4v, u);
  }
}

// ---------------- CSR build ----------------

// vectorized histogram: 4 edges/thread via int4
__global__ void nf_hist(const int* __restrict__ out_edges, int* __restrict__ counts, int E) {
  const int t4 = (blockIdx.x * blockDim.x + threadIdx.x) * 4;
  if (t4 + 3 < E) {
    const int4 v = *(const int4*)(out_edges + t4);
    atomicAdd(&counts[v.x], 1);
    atomicAdd(&counts[v.y], 1);
    atomicAdd(&counts[v.z], 1);
    atomicAdd(&counts[v.w], 1);
  } else {
    for (int i = t4; i < E; ++i) atomicAdd(&counts[out_edges[i]], 1);
  }
}

__global__ void nf_alloc(const int* __restrict__ counts, int* __restrict__ offsets,
                         int* __restrict__ cursor, int* __restrict__ total, int N) {
  const int i = blockIdx.x * blockDim.x + threadIdx.x;
  const int lane = threadIdx.x & 63;
  int c = (i < N) ? counts[i] : 0;
  int sc = c;
#pragma unroll
  for (int d = 1; d < 64; d <<= 1) {
    int v = __shfl_up(sc, d);
    if (lane >= d) sc += v;
  }
  const int excl = sc - c;
  const int wtot = __shfl(sc, 63);
  int base = 0;
  if (lane == 0) base = atomicAdd(total, wtot);
  base = __shfl(base, 0);
  if (i < N) {
    offsets[i] = base + excl;
    cursor[i]  = base + excl;
  }
}

// ---------------- main compute ----------------
// SCATTER_MODE: 0 = CSR-ordered bf16 stream, 1 = direct f32 atomics fallback

template <int SCATTER_MODE>
__global__ __launch_bounds__(256, 2)   // cap 256: spill-free (R13-R16)
void nf_main(const int* __restrict__ in_edges,
             const int* __restrict__ out_edges,
             const float* __restrict__ ef,
             const float* __restrict__ coords,
             const float* __restrict__ W1, const float* __restrict__ b1,
             const float* __restrict__ g1, const float* __restrict__ be1,
             const float* __restrict__ W2, const float* __restrict__ b2,
             const float* __restrict__ g2, const float* __restrict__ be2,
             const float* __restrict__ W3, const float* __restrict__ b3,
             void* __restrict__ out_ch,   // mode0: unsigned[E][8] bf16x2 ; mode1: float sums (d_out)
             int* __restrict__ aux,       // mode1: counts
             int* __restrict__ cursor,    // mode0: [N]
             int E, int ntiles)
{
  // W3 A-fragments (prescaled 2log2e), per (o, lane): 16B = 8 bf16 {k=4q+j+16h}
  __shared__ __align__(16) unsigned sA3[16 * 64 * 4];   // 16 KB
  __shared__ __align__(16) float    sB3f[16 * 4 * 4];   // 2log2e*b3, f32
  __shared__ __align__(16) unsigned sC1[4][16];  // w1p[3][4], b1p[4]
  __shared__ __align__(16) unsigned sC2[4][16];  // g1p, be1p, g2p, be2p
  __shared__ __align__(16) unsigned sC3[4][4];   // b2p

  const int t    = threadIdx.x;
  const int l    = t & 63;
  const int q    = l >> 4;     // lane quad (channel/row group)
  const int ecol = l & 15;     // edge column within tile

  // ---- one-time LDS staging (identical to R7-R16, verified) ----
#pragma unroll
  for (int rep = 0; rep < 4; ++rep) {
    const int idx = rep * 256 + t;          // (o, lane)
    const int o = idx >> 6, ll = idx & 63;
    const int qq = ll >> 4, ec = ll & 15;
    uint4v w;
#pragma unroll
    for (int h = 0; h < 2; ++h)
#pragma unroll
      for (int jp = 0; jp < 2; ++jp) {
        const float lo = LOG2E_X2 * W3[(4 * qq + 2 * jp     + 16 * h) * 256 + o * 16 + ec];
        const float hi = LOG2E_X2 * W3[(4 * qq + 2 * jp + 1 + 16 * h) * 256 + o * 16 + ec];
        w[h * 2 + jp] = pack2(lo, hi);
      }
    *(uint4v*)&sA3[idx * 4] = w;
  }
  if (t < 64) {
    const int o = t >> 2, qq = t & 3;
    float4v bb;
#pragma unroll
    for (int r = 0; r < 4; ++r) bb[r] = LOG2E_X2 * b3[o * 16 + 4 * qq + r];
    *(float4v*)&sB3f[t * 4] = bb;
  }
  if (t < 4) {
    const int qq = t;
#pragma unroll
    for (int i = 0; i < 4; ++i) {
      const int base = (i < 2) ? (4 * qq + 2 * i) : (4 * qq + 16 + 2 * (i - 2));
      sC1[qq][i]      = pack2(W1[base],      W1[base + 1]);
      sC1[qq][4 + i]  = pack2(W1[32 + base], W1[33 + base]);
      sC1[qq][8 + i]  = pack2(W1[64 + base], W1[65 + base]);
      sC1[qq][12 + i] = pack2(b1[base],      b1[base + 1]);
      sC2[qq][i]      = pack2(g1[base],      g1[base + 1]);
      sC2[qq][4 + i]  = pack2(be1[base],     be1[base + 1]);
      sC2[qq][8 + i]  = pack2(g2[base],      g2[base + 1]);
      sC2[qq][12 + i] = pack2(be2[base],     be2[base + 1]);
      sC3[qq][i]      = pack2(b2[base],      b2[base + 1]);
    }
  }

  // L2 A-frags in regs (8 VGPR): A[m=ch_out][k=ch_in] = W2[k][m]
  short4v a2[2][2];
#pragma unroll
  for (int t2 = 0; t2 < 2; ++t2)
#pragma unroll
    for (int h = 0; h < 2; ++h) {
      short4v v;
#pragma unroll
      for (int j = 0; j < 4; ++j)
        v[j] = (short)f2bf(W2[(4 * q + j + 16 * h) * 32 + ecol + 16 * t2]);
      a2[t2][h] = v;
    }

  __syncthreads();

  // front: L1 -> LN1 -> L2 -> LN2 -> bh[2]
  auto front = [&](float x0, float x1, float x2, short4v* bh) {
    const uint4v w1r0 = *(const uint4v*)&sC1[q][0];
    const uint4v w1r1 = *(const uint4v*)&sC1[q][4];
    const uint4v w1r2 = *(const uint4v*)&sC1[q][8];
    const uint4v b1v  = *(const uint4v*)&sC1[q][12];
    float hv[8];
#pragma unroll
    for (int i = 0; i < 4; ++i) {
      hv[2 * i]     = bflo2f(b1v[i]) + x0 * bflo2f(w1r0[i])
                    + x1 * bflo2f(w1r1[i]) + x2 * bflo2f(w1r2[i]);
      hv[2 * i + 1] = bfhi2f(b1v[i]) + x0 * bfhi2f(w1r0[i])
                    + x1 * bfhi2f(w1r1[i]) + x2 * bfhi2f(w1r2[i]);
    }
    {
      const uint4v g1v  = *(const uint4v*)&sC2[q][0];
      const uint4v be1v = *(const uint4v*)&sC2[q][4];
      ln_relu_pack(hv, g1v, be1v, bh);
    }
    {
      const uint4v b2v = *(const uint4v*)&sC3[q][0];
#pragma unroll
      for (int t2 = 0; t2 < 2; ++t2) {
        float4v c;
        c[0] = bflo2f(b2v[t2 * 2]);     c[1] = bfhi2f(b2v[t2 * 2]);
        c[2] = bflo2f(b2v[t2 * 2 + 1]); c[3] = bfhi2f(b2v[t2 * 2 + 1]);
        c = mfma16(a2[t2][0], bh[0], c);
        c = mfma16(a2[t2][1], bh[1], c);
        hv[t2 * 4 + 0] = c[0]; hv[t2 * 4 + 1] = c[1];
        hv[t2 * 4 + 2] = c[2]; hv[t2 * 4 + 3] = c[3];
      }
    }
    {
      const uint4v g2v  = *(const uint4v*)&sC2[q][8];
      const uint4v be2v = *(const uint4v*)&sC2[q][12];
      ln_relu_pack(hv, g2v, be2v, bh);
    }
  };

  const int gwave  = (blockIdx.x * blockDim.x + t) >> 6;
  const int nwaves = (gridDim.x * blockDim.x) >> 6;

  // ---- skewed-pipeline prologue (R14-R16 structure, verified) ----
  int tile = gwave;
  bool validC = false; int oeC = 0;
  short4v bhC[2] = {};
  float4v f4C = {};
  bool validN = false; int ieN = 0, oeN = 0;
  float xN0 = 0.f, xN1 = 0.f, xN2 = 0.f;

  if (tile < ntiles) {
    const int eI = tile * 16 + ecol;
    validC = eI < E;
    const int eS = validC ? eI : 0;
    const int ie = in_edges[eS]; oeC = out_edges[eS];
    const float x0 = coords[3 * eS], x1 = coords[3 * eS + 1], x2 = coords[3 * eS + 2];
    f4C = *(const float4v*)(ef + (size_t)ie * 16 + 4 * q);
    front(x0, x1, x2, bhC);
  }
  if (tile + nwaves < ntiles) {
    const int eI = (tile + nwaves) * 16 + ecol;
    validN = eI < E;
    const int eS = validN ? eI : 0;
    ieN = in_edges[eS]; oeN = out_edges[eS];
    xN0 = coords[3 * eS]; xN1 = coords[3 * eS + 1]; xN2 = coords[3 * eS + 2];
  }

  for (; tile < ntiles; tile += nwaves) {
    const int tn  = tile + nwaves;       // tile whose front runs this iter
    const int tnn = tile + 2 * nwaves;   // tile whose idx/coords prefetch now

    // ---- issue next tile's feature gather (consumed next iteration) ----
    float4v f4N = {};
    if (tn < ntiles)
      f4N = *(const float4v*)(ef + (size_t)ieN * 16 + 4 * q);

    // ---- CSR slot for CURRENT tile ----
    int pos = 0;
    if (SCATTER_MODE == 0 && q == 0 && validC)
      pos = atomicAdd(&cursor[oeC], 1);

    // ---- prefetch tile t+2 idx/coords ----
    bool validNN = false; int ieNN = 0, oeNN = 0;
    float xNN0 = 0.f, xNN1 = 0.f, xNN2 = 0.f;
    if (tnn < ntiles) {
      const int eI = tnn * 16 + ecol;
      validNN = eI < E;
      const int eS = validNN ? eI : 0;
      ieNN = in_edges[eS]; oeNN = out_edges[eS];
      xNN0 = coords[3 * eS]; xNN1 = coords[3 * eS + 1]; xNN2 = coords[3 * eS + 2];
    }

    // ---- front(t+1): long-latency chains issue first... ----
    short4v bhN[2] = {};
    if (tn < ntiles)
      front(xN0, xN1, xN2, bhN);

    // ---- ...epilogue(t): independent ILP-rich stream fills the stalls ----
    const float sumf = (f4C[0] + f4C[1]) + (f4C[2] + f4C[3]);
#pragma unroll
    for (int og = 0; og < 4; ++og) {
      float pr[4];
#pragma unroll
      for (int r = 0; r < 4; ++r) {
        const int o = og * 4 + r;
        const uint4v av = *(const uint4v*)&sA3[(o * 64 + l) * 4];
        float4v c = *(const float4v*)&sB3f[(o * 4 + q) * 4];
        uint2v t0; t0[0] = av[0]; t0[1] = av[1];
        uint2v t1; t1[0] = av[2]; t1[1] = av[3];
        const short4v a30 = __builtin_bit_cast(short4v, t0);
        const short4v a31 = __builtin_bit_cast(short4v, t1);
        c = mfma16(a30, bhC[0], c);
        c = mfma16(a31, bhC[1], c);
        float dot = 0.f;
#pragma unroll
        for (int j = 0; j < 4; ++j) {
          const float e = __builtin_amdgcn_exp2f(c[j]);
          dot = fmaf(f4C[j], __builtin_amdgcn_rcpf(e + 1.0f), dot);
        }
        pr[r] = fmaf(-2.0f, dot, sumf);
      }
#pragma unroll
      for (int r = 0; r < 4; ++r) {
        pr[r] += __shfl_xor(pr[r], 16);
        pr[r] += __shfl_xor(pr[r], 32);
      }
      if (SCATTER_MODE == 0) {
        if (q == 0 && validC) {
          uint2v s;
          s[0] = packc(pr[0], pr[1]);
          s[1] = packc(pr[2], pr[3]);
          *(uint2v*)((unsigned*)out_ch + (size_t)pos * 8 + og * 2) = s;
        }
      } else {
        if (q == 0 && validC) {
          float* sums = (float*)out_ch;
#pragma unroll
          for (int r = 0; r < 4; ++r)
            atomicAdd(&sums[(size_t)oeC * 16 + og * 4 + r], pr[r]);
        }
      }
    }
    if (SCATTER_MODE == 1) {
      if (q == 0 && validC) atomicAdd(&aux[oeC], 1);
    }

    // ---- rotate pipeline state ----
    bhC[0] = bhN[0]; bhC[1] = bhN[1];
    f4C = f4N; oeC = oeN; validC = validN;
    ieN = ieNN; oeN = oeNN; validN = validNN;
    xN0 = xNN0; xN1 = xNN1; xN2 = xNN2;
  }
}

// ---------------- per-node reduce (CSR path, bf16 rows) ----------------
// 2 threads/node, each loads uint4 (16B = 8 channels) per CSR row.

__global__ __launch_bounds__(256)
void nf_reduce(const uint4v* __restrict__ out_chb4, const int* __restrict__ counts,
               const int* __restrict__ offsets, float* __restrict__ out, int N) {
  const int gid  = blockIdx.x * 128 + (threadIdx.x >> 1);  // node
  const int half = threadIdx.x & 1;                        // channels 8h..8h+7
  if (gid >= N) return;
  const int deg = counts[gid];
  const int off = offsets[gid];
  float a[8] = {0.f, 0.f, 0.f, 0.f, 0.f, 0.f, 0.f, 0.f};
  for (int d = 0; d < deg; ++d) {
    const uint4v u = out_chb4[(size_t)(off + d) * 2 + half];
#pragma unroll
    for (int p = 0; p < 4; ++p) {
      a[2 * p]     += bflo2f(u[p]);
      a[2 * p + 1] += bfhi2f(u[p]);
    }
  }
  const float inv = 1.0f / fmaxf((float)deg, 1.0f);
  float4v r0, r1;
#pragma unroll
  for (int p = 0; p < 4; ++p) { r0[p] = a[p] * inv; r1[p] = a[4 + p] * inv; }
  float* dst = out + (size_t)gid * 16 + 8 * half;
  *(float4v*)dst       = r0;
  *(float4v*)(dst + 4) = r1;
}

// fallback divide
__global__ void nf_final(float* __restrict__ out, const int* __restrict__ counts, int n) {
  int i = blockIdx.x * blockDim.x + threadIdx.x;
  if (i < n) {
    float c = (float)counts[i >> 4];
    out[i] = out[i] / fmaxf(c, 1.0f);
  }
}

extern "C" void kernel_launch(void* const* d_in, const int* in_sizes, int n_in,
                              void* d_out, int out_size, void* d_ws, size_t ws_size,
                              hipStream_t stream) {
  const int*   in_edges  = (const int*)d_in[0];
  const int*   out_edges = (const int*)d_in[1];
  const float* ef        = (const float*)d_in[2];
  const float* coords    = (const float*)d_in[3];
  const float* W1  = (const float*)d_in[4];
  const float* b1  = (const float*)d_in[5];
  const float* g1  = (const float*)d_in[6];
  const float* be1 = (const float*)d_in[7];
  const float* W2  = (const float*)d_in[8];
  const float* b2  = (const float*)d_in[9];
  const float* g2  = (const float*)d_in[10];
  const float* be2 = (const float*)d_in[11];
  const float* W3  = (const float*)d_in[12];
  const float* b3  = (const float*)d_in[13];

  const int E = in_sizes[0];
  const int N = in_sizes[2] / 16;
  const int ntiles = (E + 15) / 16;
  float* out = (float*)d_out;

  // ws: out_chb [8E u32 bf16x2] | counts [N] | total [1] | offsets [N] | cursor [N]
  const size_t need = ((size_t)E * 8 + 3 * (size_t)N + 1) * 4;

  if (ws_size >= need) {
    unsigned* out_chb = (unsigned*)d_ws;
    int*      counts  = (int*)(out_chb + (size_t)E * 8);
    int*      total   = counts + N;
    int*      offsets = total + 1;
    int*      cursor  = offsets + N;

    // zero counts + total only (offsets/cursor fully written by nf_alloc)
    (void)hipMemsetAsync(counts, 0, ((size_t)N + 1) * sizeof(int), stream);
    nf_hist<<<(E / 4 + 255) / 256 + 1, 256, 0, stream>>>(out_edges, counts, E);
    nf_alloc<<<(N + 255) / 256, 256, 0, stream>>>(counts, offsets, cursor, total, N);
    nf_main<0><<<1024, 256, 0, stream>>>(in_edges, out_edges, ef, coords,
                                         W1, b1, g1, be1, W2, b2, g2, be2, W3, b3,
                                         out_chb, nullptr, cursor, E, ntiles);
    nf_reduce<<<(N + 127) / 128, 256, 0, stream>>>((const uint4v*)out_chb, counts,
                                                   offsets, out, N);
  } else {
    // fallback: direct f32 atomics
    int* counts = (int*)d_ws;
    (void)hipMemsetAsync(out, 0, (size_t)out_size * sizeof(float), stream);
    (void)hipMemsetAsync(counts, 0, (size_t)N * sizeof(int), stream);
    nf_main<1><<<1024, 256, 0, stream>>>(in_edges, out_edges, ef, coords,
                                         W1, b1, g1, be1, W2, b2, g2, be2, W3, b3,
                                         out, counts, nullptr, E, ntiles);
    nf_final<<<(out_size + 255) / 256, 256, 0, stream>>>(out, counts, out_size);
  }
}